// Round 3
// baseline (996.255 us; speedup 1.0000x reference)
//
#include <hip/hip_runtime.h>

#define BB 64
#define TT 1024
#define CC 256

typedef short v8s __attribute__((ext_vector_type(8)));
typedef float v4f __attribute__((ext_vector_type(4)));

#define REP8(X) X(0) X(1) X(2) X(3) X(4) X(5) X(6) X(7)

// fp32 -> bf16 round-to-nearest-even (finite inputs)
static __device__ __forceinline__ short f2bf(float f) {
  unsigned u = __float_as_uint(f);
  return (short)((u + 0x7FFFu + ((u >> 16) & 1u)) >> 16);
}

// LDS-only barrier: lgkmcnt(0) + s_barrier, no vmcnt drain.
static __device__ __forceinline__ void fast_barrier() {
  asm volatile("s_waitcnt lgkmcnt(0)\n\ts_barrier" ::: "memory");
}

// TWO chains per block: 1024 thr = 16 waves; chain cid = tid>>9 (8 waves
// each), grid = BB/2.  Rationale (R0/R1/R2 evidence): per-step time is
// ~1150 cyc of which only ~300 are busy — fixed serial latency (barrier ->
// ds_read -> MFMA chain -> VALU tail -> ds_write -> barrier) dominates and
// is invariant to intra-chain restructuring.  Two independent chains in one
// block overlap those latencies: while chain A waits, chain B issues.
// Per chain: R1's proven folded 8-wave structure. Wave w owns cols
// {w*32+nl, +16}; W = exp(trans) register-resident as 16 bf16 B-fragments
// (64 VGPR; ~110 total, fits the 128 cap at 4 waves/SIMD).  Each wave:
//   - prefetches its own e values (distance 2, alternating f/g regs),
//   - computes E = exp(e) in the MFMA shadow,
//   - writes P_t (bf16, quads 0/1) and s_scale (ctid 0),
//   - DEFERS alpha_t = log(E*r) + C_{t-1} one step (quads 2/3 store it in
//     the next step's latency shadow).
// Recurrence (exp domain): P_t = E_t (.) (W^T P_{t-1}) / sigma_t,
//   sigma_t = P_{t-1}[0] (fp32 via s_scale), C_t = C_{t-1} + log sigma_t,
//   alpha_t = log(E_t (.) W^T P_{t-1}) + C_{t-1}  (exact: sigma cancels).
__global__ __launch_bounds__(1024, 4)
void crf_fwd(const float* __restrict__ emis,      // [B,T,C]
             const float* __restrict__ trans,     // [B,C,C]
             const int* __restrict__ seq_lens,    // [B]
             float* __restrict__ out_alpha,       // [B,T,C]
             float* __restrict__ out_logz)        // [B]
{
  const int tid = threadIdx.x;
  const int cid = tid >> 9;        // chain 0/1
  const int ctid = tid & 511;      // thread id within chain
  const int lane = tid & 63;
  const int wv = ctid >> 6;        // 0..7 within chain
  const int quad = lane >> 4;
  const int nl = lane & 15;
  const int k0q = quad * 8;
  const int col0 = wv * 32 + nl;
  const int col1 = col0 + 16;
  const int b = blockIdx.x * 2 + cid;

  __shared__ unsigned short __align__(16) s_pbf[2][2][CC];  // [cid][dbuf]
  __shared__ float __align__(16) s_last[2][CC];             // alpha at L-1
  __shared__ float s_scale[2][2];                           // sigma (fp32)

  const float* eb = emis + (size_t)b * TT * CC;
  float* ab = out_alpha + (size_t)b * TT * CC;
  const int L = seq_lens[b];

  // ---- L3 pre-warm: stream both chains' 2 MB emission slab once ----
  {
    const float4* e4 = (const float4*)(emis + (size_t)(blockIdx.x * 2) * TT * CC);
    float acc = 0.f;
    #pragma unroll 4
    for (int i = tid; i < 2 * TT * CC / 4; i += 1024) {
      float4 v = e4[i];
      acc += (v.x + v.y) + (v.z + v.w);
    }
    if (acc == 1.25e38f) s_scale[1][1] = acc;   // never true; defeats DCE
  }

  // ---- B fragments: W = exp(trans), register-resident bf16 ----
#define DECLB(q) v8s B0_##q, B1_##q;
  REP8(DECLB)
  {
    const float* tb = trans + (size_t)b * CC * CC;
    const int n0 = col0;
#define INITB(q) { \
    const float* pp = tb + (size_t)(q * 32 + k0q) * CC + n0; \
    B0_##q = (v8s){ f2bf(__expf(pp[0*CC])), f2bf(__expf(pp[1*CC])), \
                    f2bf(__expf(pp[2*CC])), f2bf(__expf(pp[3*CC])), \
                    f2bf(__expf(pp[4*CC])), f2bf(__expf(pp[5*CC])), \
                    f2bf(__expf(pp[6*CC])), f2bf(__expf(pp[7*CC])) }; \
    const float* qq = pp + 16; \
    B1_##q = (v8s){ f2bf(__expf(qq[0*CC])), f2bf(__expf(qq[1*CC])), \
                    f2bf(__expf(qq[2*CC])), f2bf(__expf(qq[3*CC])), \
                    f2bf(__expf(qq[4*CC])), f2bf(__expf(qq[5*CC])), \
                    f2bf(__expf(qq[6*CC])), f2bf(__expf(qq[7*CC])) }; }
    REP8(INITB)
  }

  // ---- prologue: t = 0 ----
  float a00 = eb[0];
  float e00 = eb[col0];
  float e01 = eb[col1];
  if (quad >= 2) {
    int cc2 = col0 + ((quad - 2) << 4);
    float ev = (quad == 3) ? e01 : e00;
    ab[cc2] = ev;                                  // alpha_0 exact
    if (L == 1) s_last[cid][cc2] = ev;
  }
  if (quad < 2)
    s_pbf[cid][0][col0 + (quad << 4)] =
        (unsigned short)f2bf(__expf((quad ? e01 : e00) - a00));
  if (ctid == 0) s_scale[cid][0] = 1.0f;           // sigma_1 = P_0[0]
  float C = a00, pC = a00, pv0 = 1.0f, pv1 = 1.0f;
  float f0 = eb[CC + col0],     f1 = eb[CC + col1];      // e[1]
  float g0 = eb[2 * CC + col0], g1 = eb[2 * CC + col1];  // e[2]
  const v4f z4 = {0.f, 0.f, 0.f, 0.f};
  __syncthreads();

  // ---- step macros ----
#define MFA_Z(q) { v8s a_ = *(const v8s*)(const void*)(pbR + q * 32 + k0q); \
    c0a = __builtin_amdgcn_mfma_f32_16x16x32_bf16(a_, B0_##q, z4, 0, 0, 0); \
    c1a = __builtin_amdgcn_mfma_f32_16x16x32_bf16(a_, B1_##q, z4, 0, 0, 0); }
#define MFB_Z(q) { v8s a_ = *(const v8s*)(const void*)(pbR + q * 32 + k0q); \
    c0b = __builtin_amdgcn_mfma_f32_16x16x32_bf16(a_, B0_##q, z4, 0, 0, 0); \
    c1b = __builtin_amdgcn_mfma_f32_16x16x32_bf16(a_, B1_##q, z4, 0, 0, 0); }
#define MFA(q) { v8s a_ = *(const v8s*)(const void*)(pbR + q * 32 + k0q); \
    c0a = __builtin_amdgcn_mfma_f32_16x16x32_bf16(a_, B0_##q, c0a, 0, 0, 0); \
    c1a = __builtin_amdgcn_mfma_f32_16x16x32_bf16(a_, B1_##q, c1a, 0, 0, 0); }
#define MFB(q) { v8s a_ = *(const v8s*)(const void*)(pbR + q * 32 + k0q); \
    c0b = __builtin_amdgcn_mfma_f32_16x16x32_bf16(a_, B0_##q, c0b, 0, 0, 0); \
    c1b = __builtin_amdgcn_mfma_f32_16x16x32_bf16(a_, B1_##q, c1b, 0, 0, 0); }

#define MSTEP(T, RB, WB, EA, EB) { \
    float sig = s_scale[cid][RB]; \
    const unsigned short* pbR = s_pbf[cid][RB]; \
    v4f c0a, c0b, c1a, c1b; \
    MFA_Z(0) MFB_Z(4) MFA(1) MFB(5) MFA(2) MFB(6) MFA(3) MFB(7) \
    float E0 = __expf(EA); \
    float E1 = __expf(EB); \
    int tp2 = (T) + 2; if (tp2 > TT - 1) tp2 = TT - 1; \
    EA = eb[(size_t)tp2 * CC + col0]; \
    EB = eb[(size_t)tp2 * CC + col1]; \
    float inv = __builtin_amdgcn_rcpf(sig); \
    float r0 = c0a[0] + c0b[0]; \
    float r1 = c1a[0] + c1b[0]; \
    pC = C; \
    C += __logf(sig); \
    pv0 = E0 * r0; \
    pv1 = E1 * r1; \
    float v0 = pv0 * inv; \
    float v1 = pv1 * inv; \
    if (quad < 2) \
      s_pbf[cid][WB][col0 + (quad << 4)] = (unsigned short)f2bf(quad ? v1 : v0); \
    if (ctid == 0) s_scale[cid][WB] = v0; \
  }

  // deferred alpha for step TPREV (pv0/pv1/pC hold that step's values)
#define DEFA(TPREV) { \
    float aa0 = __logf(pv0) + pC; \
    float aa1 = __logf(pv1) + pC; \
    if (quad >= 2) { \
      float av = (quad == 3) ? aa1 : aa0; \
      int cc2 = col0 + ((quad - 2) << 4); \
      ab[(size_t)(TPREV) * CC + cc2] = av; \
      if ((TPREV) == L - 1) s_last[cid][cc2] = av; \
    } \
  }

  // ---- main chain: peel step 1, then unroll-2, 1 barrier/step ----
  MSTEP(1, 0, 1, f0, f1)
  fast_barrier();
  for (int t = 2; t + 1 < TT; t += 2) {
    DEFA(t - 1)
    MSTEP(t, 1, 0, g0, g1)
    fast_barrier();
    DEFA(t)
    MSTEP(t + 1, 0, 1, f0, f1)
    fast_barrier();
  }
  DEFA(TT - 1)
  __syncthreads();

  // ---- log_Z reduction (one wave per chain) ----
  if (ctid < 64) {
    float4 v = ((const float4*)s_last[cid])[lane];
    float m = fmaxf(fmaxf(v.x, v.y), fmaxf(v.z, v.w));
    #pragma unroll
    for (int off = 32; off >= 1; off >>= 1)
      m = fmaxf(m, __shfl_xor(m, off, 64));
    float s = __expf(v.x - m) + __expf(v.y - m) + __expf(v.z - m) + __expf(v.w - m);
    #pragma unroll
    for (int off = 32; off >= 1; off >>= 1)
      s += __shfl_xor(s, off, 64);
    if (lane == 0) out_logz[b] = m + __logf(s);
  }
}

extern "C" void kernel_launch(void* const* d_in, const int* in_sizes, int n_in,
                              void* d_out, int out_size, void* d_ws, size_t ws_size,
                              hipStream_t stream) {
  const float* emis = (const float*)d_in[0];
  const float* trans = (const float*)d_in[1];
  const int* seq_lens = (const int*)d_in[2];
  float* out_alpha = (float*)d_out;
  float* out_logz = out_alpha + (size_t)BB * TT * CC;
  hipLaunchKernelGGL(crf_fwd, dim3(BB / 2), dim3(1024), 0, stream,
                     emis, trans, seq_lens, out_alpha, out_logz);
}

// Round 4
// 540.279 us; speedup vs baseline: 1.8440x; 1.8440x over previous
//
#include <hip/hip_runtime.h>

#define BB 64
#define TT 1024
#define CC 256

typedef short v8s __attribute__((ext_vector_type(8)));
typedef int   v4i __attribute__((ext_vector_type(4)));
typedef float v4f __attribute__((ext_vector_type(4)));

#define REP8(X) X(0) X(1) X(2) X(3) X(4) X(5) X(6) X(7)

// fp32 -> bf16 round-to-nearest-even (finite inputs)
static __device__ __forceinline__ short f2bf(float f) {
  unsigned u = __float_as_uint(f);
  return (short)((u + 0x7FFFu + ((u >> 16) & 1u)) >> 16);
}

// LDS-only barrier: lgkmcnt(0) + s_barrier, no vmcnt drain.
static __device__ __forceinline__ void fast_barrier() {
  asm volatile("s_waitcnt lgkmcnt(0)\n\ts_barrier" ::: "memory");
}

// 768 thr = 12 waves per block, one block per batch chain, 1 barrier/step.
// (R0 structure — best measured; R1/R2/R3 structural rewrites all lost.)
// Waves 0-7 : MFMA-only. Wave w owns cols {w*32+nl, +16}; W = exp(trans)
//             register-resident as 16 named bf16 B-fragments.
//             Step: ds_read A(P_{t-1}) -> 16 MFMA -> v=(E*r)*rcp(sig) ->
//             bf16 ds_write. sigma = P_{t-1}[0] extracted from the q=0
//             A-fragment via readfirstlane (s_scale LDS round-trip removed).
// Waves 8-11: helpers, lane j = tid-512. Prefetch e (distance 2, unroll-2
//             alternating regs), stage E_{t+1}=exp(e_{t+1}) one step ahead
//             (s_E dbuf), compute deferred alpha_{t-1} = log(P bf16) + C and
//             store, track C += log(sigma), s_last. sigma read as bf16 from
//             s_pbf[RB][0] — same bits as MFMA waves' readfirstlane value,
//             so the rescale cancellation in alpha stays exact.
// Recurrence (exp domain): P_t = E_t (.) (W^T P_{t-1}) / sigma_t,
//   sigma_t = P_{t-1}[0] (bf16), C_t = C_{t-1} + log sigma_t,
//   alpha_t = log P_t + C_t.  Range: P in [e^-34, e^25] worst case — safe.
__global__ __launch_bounds__(768, 3)
void crf_fwd(const float* __restrict__ emis,      // [B,T,C]
             const float* __restrict__ trans,     // [B,C,C]
             const int* __restrict__ seq_lens,    // [B]
             float* __restrict__ out_alpha,       // [B,T,C]
             float* __restrict__ out_logz)        // [B]
{
  const int b = blockIdx.x;
  const int tid = threadIdx.x;
  const int lane = tid & 63;
  const int wv = tid >> 6;        // 0..7 MFMA, 8..11 helper
  const int quad = lane >> 4;
  const int nl = lane & 15;
  const int k0q = quad * 8;
  const int col0 = (wv & 7) * 32 + nl;
  const int col1 = col0 + 16;
  const int j = tid - 512;        // helper column (negative for MFMA waves)

  __shared__ unsigned short __align__(16) s_pbf[2][CC];  // P (bf16), dbuf
  __shared__ float s_E[2][CC];                           // staged exp(e_t)
  __shared__ float __align__(16) s_last[CC];             // alpha at L-1

  const float* eb = emis + (size_t)b * TT * CC;
  float* ab = out_alpha + (size_t)b * TT * CC;
  const int L = seq_lens[b];

  // ---- B fragments (declared for all; initialized/used only by wv<8) ----
#define DECLB(q) v8s B0_##q, B1_##q;
  REP8(DECLB)

  float C = 0.f, LA = 0.f, LB = 0.f;   // helper state

  if (wv < 8) {
    const float* tb = trans + (size_t)b * CC * CC;
    const int n0 = col0;
#define INITB(q) { \
    const float* pp = tb + (size_t)(q * 32 + k0q) * CC + n0; \
    B0_##q = (v8s){ f2bf(__expf(pp[0*CC])), f2bf(__expf(pp[1*CC])), \
                    f2bf(__expf(pp[2*CC])), f2bf(__expf(pp[3*CC])), \
                    f2bf(__expf(pp[4*CC])), f2bf(__expf(pp[5*CC])), \
                    f2bf(__expf(pp[6*CC])), f2bf(__expf(pp[7*CC])) }; \
    const float* qq = pp + 16; \
    B1_##q = (v8s){ f2bf(__expf(qq[0*CC])), f2bf(__expf(qq[1*CC])), \
                    f2bf(__expf(qq[2*CC])), f2bf(__expf(qq[3*CC])), \
                    f2bf(__expf(qq[4*CC])), f2bf(__expf(qq[5*CC])), \
                    f2bf(__expf(qq[6*CC])), f2bf(__expf(qq[7*CC])) }; }
    REP8(INITB)
  } else {
    // ---- helper prologue: t = 0 state ----
    float e0j = eb[j];
    float a00 = eb[0];
    ab[j] = e0j;                                   // alpha_0 exact
    C = a00;                                       // C_0
    s_pbf[0][j] = (unsigned short)f2bf(__expf(e0j - a00));
    // note: j==0 gives f2bf(exp(0)) = 1.0 exactly -> sigma_1 = 1.0
    if (L == 1) s_last[j] = e0j;
    s_E[1][j] = __expf(eb[CC + j]);                // E_1 for step t=1
    LB = eb[2 * CC + j];                           // e[2] in flight
  }
  const v4f z4 = {0.f, 0.f, 0.f, 0.f};
  __syncthreads();

  // ---- step macros ----
#define MFA(q) { v8s a_ = *(const v8s*)(const void*)(pbR + q * 32 + k0q); \
    c0a = __builtin_amdgcn_mfma_f32_16x16x32_bf16(a_, B0_##q, c0a, 0, 0, 0); \
    c1a = __builtin_amdgcn_mfma_f32_16x16x32_bf16(a_, B1_##q, c1a, 0, 0, 0); }
#define MFB(q) { v8s a_ = *(const v8s*)(const void*)(pbR + q * 32 + k0q); \
    c0b = __builtin_amdgcn_mfma_f32_16x16x32_bf16(a_, B0_##q, c0b, 0, 0, 0); \
    c1b = __builtin_amdgcn_mfma_f32_16x16x32_bf16(a_, B1_##q, c1b, 0, 0, 0); }
#define MFB_Z(q) { v8s a_ = *(const v8s*)(const void*)(pbR + q * 32 + k0q); \
    c0b = __builtin_amdgcn_mfma_f32_16x16x32_bf16(a_, B0_##q, z4, 0, 0, 0); \
    c1b = __builtin_amdgcn_mfma_f32_16x16x32_bf16(a_, B1_##q, z4, 0, 0, 0); }

#define MSTEP(T, RB, WB) { \
    const unsigned short* pbR = s_pbf[RB]; \
    v8s a0 = *(const v8s*)(const void*)(pbR + k0q);       /* q=0 chunk */ \
    float E0 = s_E[WB][col0]; \
    float E1 = s_E[WB][col1]; \
    unsigned pf = (unsigned)__builtin_amdgcn_readfirstlane(((v4i)a0)[0]); \
    float sig = __uint_as_float(pf << 16);                /* P_{t-1}[0] */ \
    float inv = __builtin_amdgcn_rcpf(sig); \
    v4f c0a, c0b, c1a, c1b; \
    c0a = __builtin_amdgcn_mfma_f32_16x16x32_bf16(a0, B0_0, z4, 0, 0, 0); \
    c1a = __builtin_amdgcn_mfma_f32_16x16x32_bf16(a0, B1_0, z4, 0, 0, 0); \
    MFB_Z(4) MFA(1) MFB(5) MFA(2) MFB(6) MFA(3) MFB(7) \
    float r0 = c0a[0] + c0b[0]; \
    float r1 = c1a[0] + c1b[0]; \
    float v0 = (E0 * r0) * inv; \
    float v1 = (E1 * r1) * inv; \
    if (quad < 2) \
      s_pbf[WB][col0 + (quad << 4)] = (unsigned short)f2bf(quad ? v1 : v0); \
  }

  // helper: at step T stage E_{T+1} into s_E[(T+1)&1] == s_E[RB]
#define HSTEP(T, RB, WB, LDREG, USEREG) { \
    int tp2 = (T) + 2; if (tp2 > TT - 1) tp2 = TT - 1; \
    LDREG = eb[(size_t)tp2 * CC + j]; \
    unsigned short sg = s_pbf[RB][0];                     /* sigma bf16 */ \
    float sig = __uint_as_float(((unsigned)sg) << 16); \
    float P = __uint_as_float(((unsigned)s_pbf[RB][j]) << 16); \
    float a_prev = __logf(P) + C; \
    if ((T) >= 2) ab[(size_t)((T) - 1) * CC + j] = a_prev; \
    if ((T) == L) s_last[j] = a_prev; \
    C += __logf(sig); \
    if ((T) < TT - 1) s_E[RB][j] = __expf(USEREG); \
  }

  // ---- main chain: unroll-2, one fast_barrier per step ----
  for (int t = 1; t + 1 < TT; t += 2) {
    if (wv < 8) { MSTEP(t, 0, 1) } else { HSTEP(t, 0, 1, LA, LB) }
    fast_barrier();
    if (wv < 8) { MSTEP(t + 1, 1, 0) } else { HSTEP(t + 1, 1, 0, LB, LA) }
    fast_barrier();
  }
  // tail step t = TT-1 (odd): RB=0, WB=1
  if (wv < 8) { MSTEP(TT - 1, 0, 1) } else { HSTEP(TT - 1, 0, 1, LA, LB) }
  fast_barrier();

  // ---- epilogue: alpha_{TT-1} by helpers, then log_Z ----
  if (wv >= 8) {
    float P = __uint_as_float(((unsigned)s_pbf[(TT - 1) & 1][j]) << 16);
    float a_last = __logf(P) + C;                  // C == C_{TT-1}
    ab[(size_t)(TT - 1) * CC + j] = a_last;
    if (L == TT) s_last[j] = a_last;
  }
  __syncthreads();

  if (tid < 64) {
    float4 v = ((const float4*)s_last)[lane];
    float m = fmaxf(fmaxf(v.x, v.y), fmaxf(v.z, v.w));
    #pragma unroll
    for (int off = 32; off >= 1; off >>= 1)
      m = fmaxf(m, __shfl_xor(m, off, 64));
    float s = __expf(v.x - m) + __expf(v.y - m) + __expf(v.z - m) + __expf(v.w - m);
    #pragma unroll
    for (int off = 32; off >= 1; off >>= 1)
      s += __shfl_xor(s, off, 64);
    if (lane == 0) out_logz[b] = m + __logf(s);
  }
}

extern "C" void kernel_launch(void* const* d_in, const int* in_sizes, int n_in,
                              void* d_out, int out_size, void* d_ws, size_t ws_size,
                              hipStream_t stream) {
  const float* emis = (const float*)d_in[0];
  const float* trans = (const float*)d_in[1];
  const int* seq_lens = (const int*)d_in[2];
  float* out_alpha = (float*)d_out;
  float* out_logz = out_alpha + (size_t)BB * TT * CC;
  hipLaunchKernelGGL(crf_fwd, dim3(BB), dim3(768), 0, stream,
                     emis, trans, seq_lens, out_alpha, out_logz);
}